// Round 20
// baseline (119.182 us; speedup 1.0000x reference)
//
#include <hip/hip_runtime.h>
#include <math.h>

#define TT 1024   // tokens
#define HH 1024   // hidden
#define MM 512    // moe intermediate
#define NE 16     // routed experts (e == NE -> shared expert)
// TOP_K = 2, SCALE = 2.5, NORM_TOPK = true

typedef _Float16 f16;
typedef _Float16 f16x4 __attribute__((ext_vector_type(4)));
typedef _Float16 f16x8 __attribute__((ext_vector_type(8)));
typedef float f32x4 __attribute__((ext_vector_type(4)));

// async global->LDS, 16B/lane, dest = wave-uniform base + lane*16 (linear)
#define GLL(g, l) __builtin_amdgcn_global_load_lds(                         \
    (const __attribute__((address_space(1))) void*)(g),                     \
    (__attribute__((address_space(3))) void*)(l), 16, 0, 0)
#define SB() __builtin_amdgcn_sched_barrier(0)
#define WAITVM(N) { SB(); asm volatile("s_waitcnt vmcnt(" #N ")"); SB(); }

// ---------------- pack x -> f16 ----------------
__global__ __launch_bounds__(256) void pack_k(const float* __restrict__ x, f16* __restrict__ xh)
{
    const int i = (blockIdx.x * 256 + threadIdx.x) * 4;
    float4 v = *(const float4*)(x + i);
    f16x4 h = { (f16)v.x, (f16)v.y, (f16)v.z, (f16)v.w };
    *(f16x4*)(xh + i) = h;
}

// ---------------- router ----------------
__global__ __launch_bounds__(256) void router_k(
    const float* __restrict__ x, const float* __restrict__ gate_w,
    int* __restrict__ counts, int* __restrict__ token_list, float* __restrict__ weight_list)
{
    const int wave = threadIdx.x >> 6;
    const int lane = threadIdx.x & 63;
    const int t = (blockIdx.x << 2) + wave;
    const float* xr = x + (size_t)t * HH;
    float xv[16];
#pragma unroll
    for (int i = 0; i < 16; ++i) xv[i] = xr[lane + (i << 6)];
    float sc[NE];
#pragma unroll
    for (int e = 0; e < NE; ++e) {
        const float* gr = gate_w + e * HH;
        float acc = 0.f;
#pragma unroll
        for (int i = 0; i < 16; ++i) acc = fmaf(xv[i], gr[lane + (i << 6)], acc);
#pragma unroll
        for (int off = 32; off > 0; off >>= 1) acc += __shfl_down(acc, off, 64);
        sc[e] = acc;
    }
    if (lane == 0) {
        float l1 = -1e30f, l2 = -1e30f; int i1 = 0, i2 = 0;
#pragma unroll
        for (int e = 0; e < NE; ++e) {
            float v = sc[e];
            if (v > l1) { l2 = l1; i2 = i1; l1 = v; i1 = e; }
            else if (v > l2) { l2 = v; i2 = e; }
        }
        float w1 = 1.f / (1.f + __expf(-l1));
        float w2 = 1.f / (1.f + __expf(-l2));
        const float inv = 2.5f / (w1 + w2 + 1e-20f);
        w1 *= inv; w2 *= inv;
        int s1 = atomicAdd(&counts[i1], 1);
        token_list[i1 * TT + s1] = t;
        weight_list[i1 * TT + s1] = w1;
        int s2 = atomicAdd(&counts[i2], 1);
        token_list[i2 * TT + s2] = t;
        weight_list[i2 * TT + s2] = w2;
    }
}

__global__ void prefix_k(const int* __restrict__ counts, int* __restrict__ offs)
{
    if (threadIdx.x == 0 && blockIdx.x == 0) {
        int acc = 0;
#pragma unroll
        for (int e = 0; e < NE; ++e) { offs[e] = acc; acc += counts[e]; }
        offs[NE] = acc;
    }
}

// ================= fused gate/up — wave-autonomous =================
// 64-thread blocks, one 32x32 output tile per wave, BK=32, NO barriers.
// Private LDS: A[32][32]f16 2KB + Bg/Bu[32][32]fp32 4KB each = 10KB x2 = 20KB
// -> 8 free-running waves/CU. 10 GLL/phase, dist-1 dbuf -> vmcnt(10) steady.
// A swizzle: unit u holds src unit u^(m&3)^((m>>2)&3)  -> b128 reads 2-way (free).
// B swizzle: r12-verified half-swap by k-group parity   -> b32 reads 2-way (free).

#define GU_ISSUE(T, AS, BG, BU) {                                           \
    GLL(pA0 + ((T) << 5), &AS[0][0]);                                       \
    GLL(pA1 + ((T) << 5), &AS[16][0]);                                      \
    _Pragma("unroll") for (int j = 0; j < 4; ++j) {                         \
        GLL(pBg[j] + (size_t)((T) << 5) * MM, &BG[j << 3][0]);              \
        GLL(pBu[j] + (size_t)((T) << 5) * MM, &BU[j << 3][0]); } }

#define GU_COMP(AS, BG, BU) {                                               \
    f16x8 af[2];                                                            \
    _Pragma("unroll") for (int f = 0; f < 2; ++f) {                         \
        const int m = (f << 4) + lm;                                        \
        af[f] = *(const f16x8*)&AS[m][(lg ^ (m & 3) ^ ((m >> 2) & 3)) << 3];\
    }                                                                       \
    _Pragma("unroll") for (int nf = 0; nf < 2; ++nf) {                      \
        const int bc = ((nf << 4) + lm) ^ ((lg & 1) << 4);                  \
        f16x8 bg, bu;                                                       \
        _Pragma("unroll") for (int j = 0; j < 8; ++j) {                     \
            bg[j] = (f16)BG[(lg << 3) + j][bc];                             \
            bu[j] = (f16)BU[(lg << 3) + j][bc]; }                           \
        _Pragma("unroll") for (int f = 0; f < 2; ++f) {                     \
            accg[f][nf] = __builtin_amdgcn_mfma_f32_16x16x32_f16(af[f], bg, accg[f][nf], 0, 0, 0); \
            accu[f][nf] = __builtin_amdgcn_mfma_f32_16x16x32_f16(af[f], bu, accu[f][nf], 0, 0, 0); } } }

// phase T: issue tile T+1 into the other buffer, wait own tile T, compute.
#define GU_PH(T, BC, BI, VC) {                                              \
    if ((T) + 1 < 32) GU_ISSUE((T) + 1, As##BI, Bg##BI, Bu##BI)             \
    WAITVM(VC)                                                              \
    GU_COMP(As##BC, Bg##BC, Bu##BC) }

__global__ __launch_bounds__(64) void gu_k(
    const f16* __restrict__ xh,
    const float* __restrict__ w_gate, const float* __restrict__ w_up,
    const float* __restrict__ ws_gate, const float* __restrict__ ws_up,
    const int* __restrict__ counts, const int* __restrict__ offs,
    const int* __restrict__ token_list, f16* __restrict__ rinter)
{
    const int F = blockIdx.x;
    const int Q = F & 7;
    const int J = F >> 3;               // 0..1151 per XCD
    int e, n0, r0;
    if (J < 1024) {                      // routed: 2 experts x 16n x 32 rowblk
        e = Q + ((J >> 9) << 3);
        const int t = J & 511;
        n0 = (t & 15) << 5;
        r0 = (t >> 4) << 5;
    } else {                             // shared slice: 64 tiles per XCD
        e = NE;
        const int idx = (Q << 6) + (J - 1024);   // 0..511
        n0 = (idx & 15) << 5;
        r0 = (idx >> 4) << 5;
    }

    int cnt, slot0;
    const float *wgp, *wup;
    if (e < NE) {
        cnt = counts[e]; slot0 = offs[e];
        wgp = w_gate + (size_t)e * HH * MM;
        wup = w_up   + (size_t)e * HH * MM;
    } else {
        cnt = TT; slot0 = 2 * TT;
        wgp = ws_gate; wup = ws_up;
    }
    if (r0 >= cnt) return;

    __shared__ f16  As0[32][32], As1[32][32];
    __shared__ float Bg0[32][32], Bg1[32][32];
    __shared__ float Bu0[32][32], Bu1[32][32];

    const int lane = threadIdx.x & 63;
    const int lm = lane & 15, lg = lane >> 4;

    // A staging: GLL i covers rows i*16..+15; lane -> row i*16+(lane>>2),
    // dest unit lane&3; src unit = (lane&3)^(row&3)^((row>>2)&3)
    //   row&3 = (lane>>2)&3, (row>>2)&3 = lane>>4  (i*16 terms vanish mod 4)
    const int swzA = ((lane & 3) ^ ((lane >> 2) & 3) ^ (lane >> 4)) << 3;
    int ar0 = r0 + (lane >> 2);        if (ar0 >= cnt) ar0 = cnt - 1;
    int ar1 = r0 + 16 + (lane >> 2);   if (ar1 >= cnt) ar1 = cnt - 1;
    const int tk0 = (e < NE) ? token_list[e * TT + ar0] : ar0;
    const int tk1 = (e < NE) ? token_list[e * TT + ar1] : ar1;
    const f16* pA0 = xh + (size_t)tk0 * HH + swzA;
    const f16* pA1 = xh + (size_t)tk1 * HH + swzA;

    // B staging: GLL j covers k-rows j*8..+7; src col unit swapped by j&1
    const float* pBg[4]; const float* pBu[4];
#pragma unroll
    for (int j = 0; j < 4; ++j) {
        const int kr = (j << 3) + (lane >> 3);
        const int sg = 4 * ((lane & 7) ^ ((j & 1) << 2));
        pBg[j] = wgp + (size_t)kr * MM + n0 + sg;
        pBu[j] = wup + (size_t)kr * MM + n0 + sg;
    }

    f32x4 accg[2][2] = {}, accu[2][2] = {};

    GU_ISSUE(0, As0, Bg0, Bu0)
#pragma unroll 1
    for (int t = 0; t < 30; t += 2) {
        GU_PH(t, 0, 1, 10)
        GU_PH(t + 1, 1, 0, 10)
    }
    GU_PH(30, 0, 1, 10)
    GU_PH(31, 1, 0, 0)

    // epilogue: silu(g)*u -> f16; C/D: col=lane&15, row=(lane>>4)*4+reg
#pragma unroll
    for (int f = 0; f < 2; ++f)
#pragma unroll
        for (int rr = 0; rr < 4; ++rr) {
            const int m = (f << 4) + (lg << 2) + rr;
            if (r0 + m < cnt) {
                f16* orow = rinter + (size_t)(slot0 + r0 + m) * MM + n0;
#pragma unroll
                for (int nf = 0; nf < 2; ++nf) {
                    float g = accg[f][nf][rr], u = accu[f][nf][rr];
                    float s = g / (1.f + __expf(-g));
                    orow[(nf << 4) + lm] = (f16)(s * u);
                }
            }
        }
}

// ================= down — wave-autonomous =================
// 32x32 tile per wave, BK=64, no barriers. LDS: A[32][64]f16 4KB +
// B[64][32]fp32 8KB = 12KB x2 = 24KB -> 6 waves/CU. 12 GLL/phase -> vmcnt(12).

#define DN_ISSUE(T, AS, BS) {                                               \
    _Pragma("unroll") for (int i = 0; i < 4; ++i)                           \
        GLL(pa[i] + ((T) << 6), &AS[i << 3][0]);                            \
    _Pragma("unroll") for (int j = 0; j < 8; ++j)                           \
        GLL(pb[j] + (size_t)((T) << 6) * HH, &BS[j << 3][0]); }

#define DN_COMP(AS, BS) {                                                   \
    _Pragma("unroll") for (int h = 0; h < 2; ++h) {                         \
        const int kb = (h << 5) + (lg << 3);                                \
        const int ko = (h << 2) + lg;                                       \
        f16x8 af[2];                                                        \
        _Pragma("unroll") for (int f = 0; f < 2; ++f) {                     \
            const int m = (f << 4) + lm;                                    \
            af[f] = *(const f16x8*)&AS[m][(ko ^ (m & 7)) << 3];             \
        }                                                                   \
        _Pragma("unroll") for (int nf = 0; nf < 2; ++nf) {                  \
            const int bc = ((nf << 4) + lm) ^ ((lg & 1) << 4);              \
            f16x8 bv;                                                       \
            _Pragma("unroll") for (int j = 0; j < 8; ++j) bv[j] = (f16)BS[kb + j][bc]; \
            _Pragma("unroll") for (int f = 0; f < 2; ++f)                   \
                acc[f][nf] = __builtin_amdgcn_mfma_f32_16x16x32_f16(af[f], bv, acc[f][nf], 0, 0, 0); } } }

#define DN_PH(T, BC, BI, VC) {                                              \
    if ((T) + 1 < 8) DN_ISSUE((T) + 1, As##BI, Bs##BI)                      \
    WAITVM(VC)                                                              \
    DN_COMP(As##BC, Bs##BC) }

__global__ __launch_bounds__(64) void down_k(
    const f16* __restrict__ rinter,
    const float* __restrict__ w_down, const float* __restrict__ ws_down,
    const int* __restrict__ counts, const int* __restrict__ offs,
    const int* __restrict__ token_list, const float* __restrict__ weight_list,
    float* __restrict__ out)
{
    const int F = blockIdx.x;
    const int Q = F & 7;
    const int J = F >> 3;               // 0..2175 per XCD
    int e, n0, r0;
    if (J < 2048) {                      // routed: 2 experts x 32n x 32 rowblk
        e = Q + ((J >> 10) << 3);
        const int t = J & 1023;
        n0 = (t & 31) << 5;
        r0 = (t >> 5) << 5;
    } else {                             // shared slice: 128 tiles per XCD
        e = NE;
        const int idx = (Q << 7) + (J - 2048);   // 0..1023
        n0 = (idx & 31) << 5;
        r0 = (idx >> 5) << 5;
    }

    int cnt, slot0; const float* wdp;
    if (e < NE) { cnt = counts[e]; slot0 = offs[e]; wdp = w_down + (size_t)e * MM * HH; }
    else        { cnt = TT; slot0 = 2 * TT; wdp = ws_down; }
    if (r0 >= cnt) return;

    __shared__ f16  As0[32][64], As1[32][64];
    __shared__ float Bs0[64][32], Bs1[64][32];

    const int lane = threadIdx.x & 63;
    const int lm = lane & 15, lg = lane >> 4;

    // A staging: GLL i covers rows i*8..+7 (slots contiguous, no tokens)
    const f16* pa[4];
#pragma unroll
    for (int i = 0; i < 4; ++i) {
        int row = r0 + (i << 3) + (lane >> 3); if (row >= cnt) row = cnt - 1;
        pa[i] = rinter + (size_t)(slot0 + row) * MM + (((lane & 7) ^ (lane >> 3)) << 3);
    }
    // B staging: GLL j covers k-rows j*8..+7
    const float* pb[8];
#pragma unroll
    for (int j = 0; j < 8; ++j) {
        const int kr = (j << 3) + (lane >> 3);
        pb[j] = wdp + (size_t)kr * HH + n0 + 4 * ((lane & 7) ^ ((j & 1) << 2));
    }

    f32x4 acc[2][2] = {};

    DN_ISSUE(0, As0, Bs0)
    DN_PH(0, 0, 1, 12) DN_PH(1, 1, 0, 12) DN_PH(2, 0, 1, 12) DN_PH(3, 1, 0, 12)
    DN_PH(4, 0, 1, 12) DN_PH(5, 1, 0, 12) DN_PH(6, 0, 1, 12) DN_PH(7, 1, 0, 0)

#pragma unroll
    for (int f = 0; f < 2; ++f)
#pragma unroll
        for (int rr = 0; rr < 4; ++rr) {
            const int m = (f << 4) + (lg << 2) + rr;
            const int row = r0 + m;
            if (row < cnt) {
                int t; float wt;
                if (e < NE) { t = token_list[e * TT + row]; wt = weight_list[e * TT + row]; }
                else        { t = row; wt = 1.f; }
                float* orow = out + (size_t)t * HH + n0;
#pragma unroll
                for (int nf = 0; nf < 2; ++nf)
                    atomicAdd(&orow[(nf << 4) + lm], wt * acc[f][nf][rr]);
            }
        }
}

extern "C" void kernel_launch(void* const* d_in, const int* in_sizes, int n_in,
                              void* d_out, int out_size, void* d_ws, size_t ws_size,
                              hipStream_t stream)
{
    const float* x       = (const float*)d_in[0];
    const float* gate_w  = (const float*)d_in[1];
    const float* w_gate  = (const float*)d_in[2];
    const float* w_up    = (const float*)d_in[3];
    const float* w_down  = (const float*)d_in[4];
    const float* ws_gate = (const float*)d_in[5];
    const float* ws_up   = (const float*)d_in[6];
    const float* ws_down = (const float*)d_in[7];
    float* out = (float*)d_out;

    // ws (r16 layout): counts[16]|offs[17] (64 ints) | token_list 16K ints |
    // weight_list 16K floats | rinter f16 [3072][512] | xh f16 [1024][1024]
    int* counts = (int*)d_ws;
    int* offs = counts + 16;
    int* token_list = counts + 64;
    float* weight_list = (float*)(counts + 64 + NE * TT);
    f16* rinter = (f16*)(counts + 64 + 2 * NE * TT);
    f16* xh = rinter + (size_t)3072 * MM;

    hipMemsetAsync(counts, 0, 64, stream);
    hipMemsetAsync(out, 0, (size_t)TT * HH * sizeof(float), stream);
    pack_k<<<dim3(TT * HH / 1024), 256, 0, stream>>>(x, xh);
    router_k<<<dim3(TT / 4), 256, 0, stream>>>(x, gate_w, counts, token_list, weight_list);
    prefix_k<<<1, 64, 0, stream>>>(counts, offs);
    gu_k<<<dim3(8 * 1152), 64, 0, stream>>>(
        xh, w_gate, w_up, ws_gate, ws_up, counts, offs, token_list, rinter);
    down_k<<<dim3(8 * 2176), 64, 0, stream>>>(
        rinter, w_down, ws_down, counts, offs, token_list, weight_list, out);
}

// Round 21
// 102.341 us; speedup vs baseline: 1.1646x; 1.1646x over previous
//
#include <hip/hip_runtime.h>
#include <math.h>

#define TT 1024   // tokens
#define HH 1024   // hidden
#define MM 512    // moe intermediate
#define NE 16     // routed experts (e == NE -> shared expert)
// TOP_K = 2, SCALE = 2.5, NORM_TOPK = true

typedef _Float16 f16;
typedef _Float16 f16x4 __attribute__((ext_vector_type(4)));
typedef _Float16 f16x8 __attribute__((ext_vector_type(8)));
typedef float f32x4 __attribute__((ext_vector_type(4)));

// async global->LDS, 16B/lane, dest = wave-uniform base + lane*16 (linear)
#define GLL(g, l) __builtin_amdgcn_global_load_lds(                         \
    (const __attribute__((address_space(1))) void*)(g),                     \
    (__attribute__((address_space(3))) void*)(l), 16, 0, 0)
#define SB() __builtin_amdgcn_sched_barrier(0)
#define WAITVM(N) { SB(); asm volatile("s_waitcnt vmcnt(" #N ")"); SB(); }
#define BARRIER() __builtin_amdgcn_s_barrier()

// ---------------- pack x -> f16 ----------------
__global__ __launch_bounds__(256) void pack_k(const float* __restrict__ x, f16* __restrict__ xh)
{
    const int i = (blockIdx.x * 256 + threadIdx.x) * 4;
    float4 v = *(const float4*)(x + i);
    f16x4 h = { (f16)v.x, (f16)v.y, (f16)v.z, (f16)v.w };
    *(f16x4*)(xh + i) = h;
}

// ---------------- router ----------------
__global__ __launch_bounds__(256) void router_k(
    const float* __restrict__ x, const float* __restrict__ gate_w,
    int* __restrict__ counts, int* __restrict__ token_list, float* __restrict__ weight_list)
{
    const int wave = threadIdx.x >> 6;
    const int lane = threadIdx.x & 63;
    const int t = (blockIdx.x << 2) + wave;
    const float* xr = x + (size_t)t * HH;
    float xv[16];
#pragma unroll
    for (int i = 0; i < 16; ++i) xv[i] = xr[lane + (i << 6)];
    float sc[NE];
#pragma unroll
    for (int e = 0; e < NE; ++e) {
        const float* gr = gate_w + e * HH;
        float acc = 0.f;
#pragma unroll
        for (int i = 0; i < 16; ++i) acc = fmaf(xv[i], gr[lane + (i << 6)], acc);
#pragma unroll
        for (int off = 32; off > 0; off >>= 1) acc += __shfl_down(acc, off, 64);
        sc[e] = acc;
    }
    if (lane == 0) {
        float l1 = -1e30f, l2 = -1e30f; int i1 = 0, i2 = 0;
#pragma unroll
        for (int e = 0; e < NE; ++e) {
            float v = sc[e];
            if (v > l1) { l2 = l1; i2 = i1; l1 = v; i1 = e; }
            else if (v > l2) { l2 = v; i2 = e; }
        }
        float w1 = 1.f / (1.f + __expf(-l1));
        float w2 = 1.f / (1.f + __expf(-l2));
        const float inv = 2.5f / (w1 + w2 + 1e-20f);
        w1 *= inv; w2 *= inv;
        int s1 = atomicAdd(&counts[i1], 1);
        token_list[i1 * TT + s1] = t;
        weight_list[i1 * TT + s1] = w1;
        int s2 = atomicAdd(&counts[i2], 1);
        token_list[i2 * TT + s2] = t;
        weight_list[i2 * TT + s2] = w2;
    }
}

__global__ void prefix_k(const int* __restrict__ counts, int* __restrict__ offs)
{
    if (threadIdx.x == 0 && blockIdx.x == 0) {
        int acc = 0;
#pragma unroll
        for (int e = 0; e < NE; ++e) { offs[e] = acc; acc += counts[e]; }
        offs[NE] = acc;
    }
}

// ================= fused gate/up =================
// BM=128, BN=32, BK=32. 256 thr, wave w owns rows 32w..32w+31 (2m x 2n frags).
// All VMEM = GLL, dist-2, 3 buffers, 4 GLL/wave/phase -> 12 outstanding,
// vmcnt(8) steady. LDS: A[128][32]f16 8KB + Bg/Bu[32][32]f32 4KB ea = 16KB x3.
// A swizzle: LDS[m][u16B] = src unit u^((m>>1)&3) -> b128 reads structural-min.
// B swizzle: parity half-swap (r16-proven) -> 2-way (free).

#define GU_ISSUE(T, AS, BG, BU) {                                           \
    GLL(pA0 + ((T) << 5), &AS[w << 5][0]);                                  \
    GLL(pA1 + ((T) << 5), &AS[(w << 5) + 16][0]);                           \
    GLL(pBg + (size_t)((T) << 5) * MM, &BG[w << 3][0]);                     \
    GLL(pBu + (size_t)((T) << 5) * MM, &BU[w << 3][0]); }

#define GU_COMP(AS, BG, BU) {                                               \
    f16x8 af[2];                                                            \
    _Pragma("unroll") for (int f = 0; f < 2; ++f) {                         \
        const int m = (w << 5) + (f << 4) + lm;                             \
        af[f] = *(const f16x8*)&AS[m][(lg ^ ((m >> 1) & 3)) << 3];          \
    }                                                                       \
    _Pragma("unroll") for (int nf = 0; nf < 2; ++nf) {                      \
        const int bc = ((nf << 4) + lm) ^ ((lg & 1) << 4);                  \
        f16x8 bg, bu;                                                       \
        _Pragma("unroll") for (int j = 0; j < 8; ++j) {                     \
            bg[j] = (f16)BG[(lg << 3) + j][bc];                             \
            bu[j] = (f16)BU[(lg << 3) + j][bc]; }                           \
        _Pragma("unroll") for (int f = 0; f < 2; ++f) {                     \
            accg[f][nf] = __builtin_amdgcn_mfma_f32_16x16x32_f16(af[f], bg, accg[f][nf], 0, 0, 0); \
            accu[f][nf] = __builtin_amdgcn_mfma_f32_16x16x32_f16(af[f], bu, accu[f][nf], 0, 0, 0); } } }

#define GU_PH(T, CB, IB, VC) {                                              \
    if ((T) + 2 < 32) GU_ISSUE((T) + 2, As##IB, Bg##IB, Bu##IB)             \
    WAITVM(VC) BARRIER();                                                   \
    GU_COMP(As##CB, Bg##CB, Bu##CB)                                         \
    BARRIER(); }

__global__ __launch_bounds__(256) void gu_k(
    const f16* __restrict__ xh,
    const float* __restrict__ w_gate, const float* __restrict__ w_up,
    const float* __restrict__ ws_gate, const float* __restrict__ ws_up,
    const int* __restrict__ counts, const int* __restrict__ offs,
    const int* __restrict__ token_list, f16* __restrict__ rinter)
{
    const int F = blockIdx.x;
    const int Q = F & 7;
    const int J = F >> 3;                // 0..271 per XCD
    int e, n0, r0;
    if (J < 256) {                        // routed: 2 experts x 16n x 8 rowblk
        e = Q + ((J >> 7) << 3);
        const int t = J & 127;
        n0 = (t & 15) << 5;
        r0 = (t >> 4) << 7;
    } else {                              // shared: 16 tiles per XCD
        e = NE;
        const int idx = (Q << 4) + (J - 256);   // 0..127
        n0 = (idx & 15) << 5;
        r0 = (idx >> 4) << 7;
    }

    int cnt, slot0;
    const float *wgp, *wup;
    if (e < NE) {
        cnt = counts[e]; slot0 = offs[e];
        wgp = w_gate + (size_t)e * HH * MM;
        wup = w_up   + (size_t)e * HH * MM;
    } else {
        cnt = TT; slot0 = 2 * TT;
        wgp = ws_gate; wup = ws_up;
    }
    if (r0 >= cnt) return;

    __shared__ f16  As0[128][32], As1[128][32], As2[128][32];
    __shared__ float Bg0[32][32], Bg1[32][32], Bg2[32][32];
    __shared__ float Bu0[32][32], Bu1[32][32], Bu2[32][32];
    __shared__ int toks[128];

    const int tid = threadIdx.x;
    if (tid < 128) {
        int i = r0 + tid; if (i >= cnt) i = cnt - 1;
        toks[tid] = (e < NE) ? token_list[e * TT + i] : i;
    }
    __syncthreads();

    const int w = tid >> 6, lane = tid & 63;
    const int lm = lane & 15, lg = lane >> 4;

    // A GLL: lane -> row base+(lane>>2), dest unit lane&3,
    // src unit = (lane&3)^((lane>>3)&3)  (realizes s(m)=(m>>1)&3)
    const int swzA = ((lane & 3) ^ ((lane >> 3) & 3)) << 3;
    const f16* pA0 = xh + (size_t)toks[(w << 5) + (lane >> 2)]      * HH + swzA;
    const f16* pA1 = xh + (size_t)toks[(w << 5) + 16 + (lane >> 2)] * HH + swzA;
    // B GLL: wave w stages k-rows 8w..8w+7; src col unit swapped by w&1
    const int kr = (w << 3) + (lane >> 3);
    const int sg = 4 * ((lane & 7) ^ ((w & 1) << 2));
    const float* pBg = wgp + (size_t)kr * MM + n0 + sg;
    const float* pBu = wup + (size_t)kr * MM + n0 + sg;

    f32x4 accg[2][2] = {}, accu[2][2] = {};

    GU_ISSUE(0, As0, Bg0, Bu0)
    GU_ISSUE(1, As1, Bg1, Bu1)

    GU_PH(0,0,2,8)  GU_PH(1,1,0,8)  GU_PH(2,2,1,8)  GU_PH(3,0,2,8)
    GU_PH(4,1,0,8)  GU_PH(5,2,1,8)  GU_PH(6,0,2,8)  GU_PH(7,1,0,8)
    GU_PH(8,2,1,8)  GU_PH(9,0,2,8)  GU_PH(10,1,0,8) GU_PH(11,2,1,8)
    GU_PH(12,0,2,8) GU_PH(13,1,0,8) GU_PH(14,2,1,8) GU_PH(15,0,2,8)
    GU_PH(16,1,0,8) GU_PH(17,2,1,8) GU_PH(18,0,2,8) GU_PH(19,1,0,8)
    GU_PH(20,2,1,8) GU_PH(21,0,2,8) GU_PH(22,1,0,8) GU_PH(23,2,1,8)
    GU_PH(24,0,2,8) GU_PH(25,1,0,8) GU_PH(26,2,1,8) GU_PH(27,0,2,8)
    GU_PH(28,1,0,8) GU_PH(29,2,1,8) GU_PH(30,0,2,4) GU_PH(31,1,0,0)

    // epilogue: silu(g)*u -> f16; C/D: col=lane&15, row=(lane>>4)*4+reg
#pragma unroll
    for (int f = 0; f < 2; ++f)
#pragma unroll
        for (int rr = 0; rr < 4; ++rr) {
            const int m = (w << 5) + (f << 4) + (lg << 2) + rr;
            if (r0 + m < cnt) {
                f16* orow = rinter + (size_t)(slot0 + r0 + m) * MM + n0;
#pragma unroll
                for (int nf = 0; nf < 2; ++nf) {
                    float g = accg[f][nf][rr], u = accu[f][nf][rr];
                    float s = g / (1.f + __expf(-g));
                    orow[(nf << 4) + lm] = (f16)(s * u);
                }
            }
        }
}

// ================= down: out[token] += weight * (rinter @ Wd) =================
// BM=128, BN=32, BK=32. 3 GLL/wave/phase -> 9 outstanding, vmcnt(6) steady.
// LDS: A[128][32]f16 8KB + B[32][32]f32 4KB = 12KB x3 = 36KB -> 4 blocks/CU.

#define DN_ISSUE(T, AS, BS) {                                               \
    GLL(pa0 + ((T) << 5), &AS[w << 5][0]);                                  \
    GLL(pa1 + ((T) << 5), &AS[(w << 5) + 16][0]);                           \
    GLL(pb + (size_t)((T) << 5) * HH, &BS[w << 3][0]); }

#define DN_COMP(AS, BS) {                                                   \
    f16x8 af[2];                                                            \
    _Pragma("unroll") for (int f = 0; f < 2; ++f) {                         \
        const int m = (w << 5) + (f << 4) + lm;                             \
        af[f] = *(const f16x8*)&AS[m][(lg ^ ((m >> 1) & 3)) << 3];          \
    }                                                                       \
    _Pragma("unroll") for (int nf = 0; nf < 2; ++nf) {                      \
        const int bc = ((nf << 4) + lm) ^ ((lg & 1) << 4);                  \
        f16x8 bv;                                                           \
        _Pragma("unroll") for (int j = 0; j < 8; ++j) bv[j] = (f16)BS[(lg << 3) + j][bc]; \
        _Pragma("unroll") for (int f = 0; f < 2; ++f)                       \
            acc[f][nf] = __builtin_amdgcn_mfma_f32_16x16x32_f16(af[f], bv, acc[f][nf], 0, 0, 0); } }

#define DN_PH(T, CB, IB, VC) {                                              \
    if ((T) + 2 < 16) DN_ISSUE((T) + 2, As##IB, Bs##IB)                     \
    WAITVM(VC) BARRIER();                                                   \
    DN_COMP(As##CB, Bs##CB)                                                 \
    BARRIER(); }

__global__ __launch_bounds__(256) void down_k(
    const f16* __restrict__ rinter,
    const float* __restrict__ w_down, const float* __restrict__ ws_down,
    const int* __restrict__ counts, const int* __restrict__ offs,
    const int* __restrict__ token_list, const float* __restrict__ weight_list,
    float* __restrict__ out)
{
    const int F = blockIdx.x;
    const int Q = F & 7;
    const int J = F >> 3;                // 0..543 per XCD
    int e, n0, r0;
    if (J < 512) {                        // routed: 2 experts x 32n x 8 rowblk
        e = Q + ((J >> 8) << 3);
        const int t = J & 255;
        n0 = (t & 31) << 5;
        r0 = (t >> 5) << 7;
    } else {                              // shared: 32 tiles per XCD
        e = NE;
        const int idx = (Q << 5) + (J - 512);   // 0..255
        n0 = (idx & 31) << 5;
        r0 = (idx >> 5) << 7;
    }

    int cnt, slot0; const float* wdp;
    if (e < NE) { cnt = counts[e]; slot0 = offs[e]; wdp = w_down + (size_t)e * MM * HH; }
    else        { cnt = TT; slot0 = 2 * TT; wdp = ws_down; }
    if (r0 >= cnt) return;

    __shared__ f16  As0[128][32], As1[128][32], As2[128][32];
    __shared__ float Bs0[32][32], Bs1[32][32], Bs2[32][32];

    const int tid = threadIdx.x;
    const int w = tid >> 6, lane = tid & 63;
    const int lm = lane & 15, lg = lane >> 4;

    const int swzA = ((lane & 3) ^ ((lane >> 3) & 3)) << 3;
    int ra = r0 + (w << 5) + (lane >> 2);       if (ra >= cnt) ra = cnt - 1;
    int rb = r0 + (w << 5) + 16 + (lane >> 2);  if (rb >= cnt) rb = cnt - 1;
    const f16* pa0 = rinter + (size_t)(slot0 + ra) * MM + swzA;
    const f16* pa1 = rinter + (size_t)(slot0 + rb) * MM + swzA;
    const int kr = (w << 3) + (lane >> 3);
    const int sg = 4 * ((lane & 7) ^ ((w & 1) << 2));
    const float* pb = wdp + (size_t)kr * HH + n0 + sg;

    f32x4 acc[2][2] = {};

    DN_ISSUE(0, As0, Bs0)
    DN_ISSUE(1, As1, Bs1)

    DN_PH(0,0,2,6)  DN_PH(1,1,0,6)  DN_PH(2,2,1,6)  DN_PH(3,0,2,6)
    DN_PH(4,1,0,6)  DN_PH(5,2,1,6)  DN_PH(6,0,2,6)  DN_PH(7,1,0,6)
    DN_PH(8,2,1,6)  DN_PH(9,0,2,6)  DN_PH(10,1,0,6) DN_PH(11,2,1,6)
    DN_PH(12,0,2,6) DN_PH(13,1,0,6) DN_PH(14,2,1,3) DN_PH(15,0,0,0)

#pragma unroll
    for (int f = 0; f < 2; ++f)
#pragma unroll
        for (int rr = 0; rr < 4; ++rr) {
            const int m = (w << 5) + (f << 4) + (lg << 2) + rr;
            const int row = r0 + m;
            if (row < cnt) {
                int t; float wt;
                if (e < NE) { t = token_list[e * TT + row]; wt = weight_list[e * TT + row]; }
                else        { t = row; wt = 1.f; }
                float* orow = out + (size_t)t * HH + n0;
#pragma unroll
                for (int nf = 0; nf < 2; ++nf)
                    atomicAdd(&orow[(nf << 4) + lm], wt * acc[f][nf][rr]);
            }
        }
}

extern "C" void kernel_launch(void* const* d_in, const int* in_sizes, int n_in,
                              void* d_out, int out_size, void* d_ws, size_t ws_size,
                              hipStream_t stream)
{
    const float* x       = (const float*)d_in[0];
    const float* gate_w  = (const float*)d_in[1];
    const float* w_gate  = (const float*)d_in[2];
    const float* w_up    = (const float*)d_in[3];
    const float* w_down  = (const float*)d_in[4];
    const float* ws_gate = (const float*)d_in[5];
    const float* ws_up   = (const float*)d_in[6];
    const float* ws_down = (const float*)d_in[7];
    float* out = (float*)d_out;

    // ws (r16 layout): counts[16]|offs[17] (64 ints) | token_list 16K ints |
    // weight_list 16K floats | rinter f16 [3072][512] | xh f16 [1024][1024]
    int* counts = (int*)d_ws;
    int* offs = counts + 16;
    int* token_list = counts + 64;
    float* weight_list = (float*)(counts + 64 + NE * TT);
    f16* rinter = (f16*)(counts + 64 + 2 * NE * TT);
    f16* xh = rinter + (size_t)3072 * MM;

    hipMemsetAsync(counts, 0, 64, stream);
    hipMemsetAsync(out, 0, (size_t)TT * HH * sizeof(float), stream);
    pack_k<<<dim3(TT * HH / 1024), 256, 0, stream>>>(x, xh);
    router_k<<<dim3(TT / 4), 256, 0, stream>>>(x, gate_w, counts, token_list, weight_list);
    prefix_k<<<1, 64, 0, stream>>>(counts, offs);
    gu_k<<<dim3(8 * 272), 256, 0, stream>>>(
        xh, w_gate, w_up, ws_gate, ws_up, counts, offs, token_list, rinter);
    down_k<<<dim3(8 * 544), 256, 0, stream>>>(
        rinter, w_down, ws_down, counts, offs, token_list, weight_list, out);
}

// Round 22
// 99.477 us; speedup vs baseline: 1.1981x; 1.0288x over previous
//
#include <hip/hip_runtime.h>
#include <math.h>

#define TT 1024   // tokens
#define HH 1024   // hidden
#define MM 512    // moe intermediate
#define NE 16     // routed experts (e == NE -> shared expert)
// TOP_K = 2, SCALE = 2.5, NORM_TOPK = true

typedef _Float16 f16;
typedef _Float16 f16x4 __attribute__((ext_vector_type(4)));
typedef _Float16 f16x8 __attribute__((ext_vector_type(8)));
typedef float f32x4 __attribute__((ext_vector_type(4)));

// async global->LDS, 16B/lane, dest = wave-uniform base + lane*16 (linear)
#define GLL(g, l) __builtin_amdgcn_global_load_lds(                         \
    (const __attribute__((address_space(1))) void*)(g),                     \
    (__attribute__((address_space(3))) void*)(l), 16, 0, 0)
#define SB() __builtin_amdgcn_sched_barrier(0)
#define WAITVM(N) { SB(); asm volatile("s_waitcnt vmcnt(" #N ")"); SB(); }
#define BARRIER() __builtin_amdgcn_s_barrier()

// ---------------- pack x -> f16 ----------------
__global__ __launch_bounds__(256) void pack_k(const float* __restrict__ x, f16* __restrict__ xh)
{
    const int i = (blockIdx.x * 256 + threadIdx.x) * 4;
    float4 v = *(const float4*)(x + i);
    f16x4 h = { (f16)v.x, (f16)v.y, (f16)v.z, (f16)v.w };
    *(f16x4*)(xh + i) = h;
}

// ---------------- router ----------------
__global__ __launch_bounds__(256) void router_k(
    const float* __restrict__ x, const float* __restrict__ gate_w,
    int* __restrict__ counts, int* __restrict__ token_list, float* __restrict__ weight_list)
{
    const int wave = threadIdx.x >> 6;
    const int lane = threadIdx.x & 63;
    const int t = (blockIdx.x << 2) + wave;
    const float* xr = x + (size_t)t * HH;
    float xv[16];
#pragma unroll
    for (int i = 0; i < 16; ++i) xv[i] = xr[lane + (i << 6)];
    float sc[NE];
#pragma unroll
    for (int e = 0; e < NE; ++e) {
        const float* gr = gate_w + e * HH;
        float acc = 0.f;
#pragma unroll
        for (int i = 0; i < 16; ++i) acc = fmaf(xv[i], gr[lane + (i << 6)], acc);
#pragma unroll
        for (int off = 32; off > 0; off >>= 1) acc += __shfl_down(acc, off, 64);
        sc[e] = acc;
    }
    if (lane == 0) {
        float l1 = -1e30f, l2 = -1e30f; int i1 = 0, i2 = 0;
#pragma unroll
        for (int e = 0; e < NE; ++e) {
            float v = sc[e];
            if (v > l1) { l2 = l1; i2 = i1; l1 = v; i1 = e; }
            else if (v > l2) { l2 = v; i2 = e; }
        }
        float w1 = 1.f / (1.f + __expf(-l1));
        float w2 = 1.f / (1.f + __expf(-l2));
        const float inv = 2.5f / (w1 + w2 + 1e-20f);
        w1 *= inv; w2 *= inv;
        int s1 = atomicAdd(&counts[i1], 1);
        token_list[i1 * TT + s1] = t;
        weight_list[i1 * TT + s1] = w1;
        int s2 = atomicAdd(&counts[i2], 1);
        token_list[i2 * TT + s2] = t;
        weight_list[i2 * TT + s2] = w2;
    }
}

__global__ void prefix_k(const int* __restrict__ counts, int* __restrict__ offs)
{
    if (threadIdx.x == 0 && blockIdx.x == 0) {
        int acc = 0;
#pragma unroll
        for (int e = 0; e < NE; ++e) { offs[e] = acc; acc += counts[e]; }
        offs[NE] = acc;
    }
}

// ================= fused gate/up (r21-exact) =================
// BM=128, BN=32, BK=32. 256 thr, wave w owns rows 32w..32w+31.
// dist-2, 3 buffers, 4 GLL/wave/phase -> vmcnt(8) steady.

#define GU_ISSUE(T, AS, BG, BU) {                                           \
    GLL(pA0 + ((T) << 5), &AS[w << 5][0]);                                  \
    GLL(pA1 + ((T) << 5), &AS[(w << 5) + 16][0]);                           \
    GLL(pBg + (size_t)((T) << 5) * MM, &BG[w << 3][0]);                     \
    GLL(pBu + (size_t)((T) << 5) * MM, &BU[w << 3][0]); }

#define GU_COMP(AS, BG, BU) {                                               \
    f16x8 af[2];                                                            \
    _Pragma("unroll") for (int f = 0; f < 2; ++f) {                         \
        const int m = (w << 5) + (f << 4) + lm;                             \
        af[f] = *(const f16x8*)&AS[m][(lg ^ ((m >> 1) & 3)) << 3];          \
    }                                                                       \
    _Pragma("unroll") for (int nf = 0; nf < 2; ++nf) {                      \
        const int bc = ((nf << 4) + lm) ^ ((lg & 1) << 4);                  \
        f16x8 bg, bu;                                                       \
        _Pragma("unroll") for (int j = 0; j < 8; ++j) {                     \
            bg[j] = (f16)BG[(lg << 3) + j][bc];                             \
            bu[j] = (f16)BU[(lg << 3) + j][bc]; }                           \
        _Pragma("unroll") for (int f = 0; f < 2; ++f) {                     \
            accg[f][nf] = __builtin_amdgcn_mfma_f32_16x16x32_f16(af[f], bg, accg[f][nf], 0, 0, 0); \
            accu[f][nf] = __builtin_amdgcn_mfma_f32_16x16x32_f16(af[f], bu, accu[f][nf], 0, 0, 0); } } }

#define GU_PH(T, CB, IB, VC) {                                              \
    if ((T) + 2 < 32) GU_ISSUE((T) + 2, As##IB, Bg##IB, Bu##IB)             \
    WAITVM(VC) BARRIER();                                                   \
    GU_COMP(As##CB, Bg##CB, Bu##CB)                                         \
    BARRIER(); }

__global__ __launch_bounds__(256) void gu_k(
    const f16* __restrict__ xh,
    const float* __restrict__ w_gate, const float* __restrict__ w_up,
    const float* __restrict__ ws_gate, const float* __restrict__ ws_up,
    const int* __restrict__ counts, const int* __restrict__ offs,
    const int* __restrict__ token_list, f16* __restrict__ rinter)
{
    const int F = blockIdx.x;
    const int Q = F & 7;
    const int J = F >> 3;                // 0..271 per XCD
    int e, n0, r0;
    if (J < 256) {
        e = Q + ((J >> 7) << 3);
        const int t = J & 127;
        n0 = (t & 15) << 5;
        r0 = (t >> 4) << 7;
    } else {
        e = NE;
        const int idx = (Q << 4) + (J - 256);
        n0 = (idx & 15) << 5;
        r0 = (idx >> 4) << 7;
    }

    int cnt, slot0;
    const float *wgp, *wup;
    if (e < NE) {
        cnt = counts[e]; slot0 = offs[e];
        wgp = w_gate + (size_t)e * HH * MM;
        wup = w_up   + (size_t)e * HH * MM;
    } else {
        cnt = TT; slot0 = 2 * TT;
        wgp = ws_gate; wup = ws_up;
    }
    if (r0 >= cnt) return;

    __shared__ f16  As0[128][32], As1[128][32], As2[128][32];
    __shared__ float Bg0[32][32], Bg1[32][32], Bg2[32][32];
    __shared__ float Bu0[32][32], Bu1[32][32], Bu2[32][32];
    __shared__ int toks[128];

    const int tid = threadIdx.x;
    if (tid < 128) {
        int i = r0 + tid; if (i >= cnt) i = cnt - 1;
        toks[tid] = (e < NE) ? token_list[e * TT + i] : i;
    }
    __syncthreads();

    const int w = tid >> 6, lane = tid & 63;
    const int lm = lane & 15, lg = lane >> 4;

    const int swzA = ((lane & 3) ^ ((lane >> 3) & 3)) << 3;
    const f16* pA0 = xh + (size_t)toks[(w << 5) + (lane >> 2)]      * HH + swzA;
    const f16* pA1 = xh + (size_t)toks[(w << 5) + 16 + (lane >> 2)] * HH + swzA;
    const int kr = (w << 3) + (lane >> 3);
    const int sg = 4 * ((lane & 7) ^ ((w & 1) << 2));
    const float* pBg = wgp + (size_t)kr * MM + n0 + sg;
    const float* pBu = wup + (size_t)kr * MM + n0 + sg;

    f32x4 accg[2][2] = {}, accu[2][2] = {};

    GU_ISSUE(0, As0, Bg0, Bu0)
    GU_ISSUE(1, As1, Bg1, Bu1)

    GU_PH(0,0,2,8)  GU_PH(1,1,0,8)  GU_PH(2,2,1,8)  GU_PH(3,0,2,8)
    GU_PH(4,1,0,8)  GU_PH(5,2,1,8)  GU_PH(6,0,2,8)  GU_PH(7,1,0,8)
    GU_PH(8,2,1,8)  GU_PH(9,0,2,8)  GU_PH(10,1,0,8) GU_PH(11,2,1,8)
    GU_PH(12,0,2,8) GU_PH(13,1,0,8) GU_PH(14,2,1,8) GU_PH(15,0,2,8)
    GU_PH(16,1,0,8) GU_PH(17,2,1,8) GU_PH(18,0,2,8) GU_PH(19,1,0,8)
    GU_PH(20,2,1,8) GU_PH(21,0,2,8) GU_PH(22,1,0,8) GU_PH(23,2,1,8)
    GU_PH(24,0,2,8) GU_PH(25,1,0,8) GU_PH(26,2,1,8) GU_PH(27,0,2,8)
    GU_PH(28,1,0,8) GU_PH(29,2,1,8) GU_PH(30,0,2,4) GU_PH(31,1,0,0)

    // epilogue: silu(g)*u -> f16; C/D: col=lane&15, row=(lane>>4)*4+reg
#pragma unroll
    for (int f = 0; f < 2; ++f)
#pragma unroll
        for (int rr = 0; rr < 4; ++rr) {
            const int m = (w << 5) + (f << 4) + (lg << 2) + rr;
            if (r0 + m < cnt) {
                f16* orow = rinter + (size_t)(slot0 + r0 + m) * MM + n0;
#pragma unroll
                for (int nf = 0; nf < 2; ++nf) {
                    float g = accg[f][nf][rr], u = accu[f][nf][rr];
                    float s = g / (1.f + __expf(-g));
                    orow[(nf << 4) + lm] = (f16)(s * u);
                }
            }
        }
}

// ================= down: BM=128, BN=64, BK=32 =================
// 4 waves; wave w owns rows 32w..+31, all 64 cols (2m x 4n frags).
// 4 GLL/wave/phase (2 A + 2 B), dist-2, 3 buffers -> vmcnt(8) steady.
// LDS: A[128][32]f16 8KB + B[32][64]f32 8KB = 16KB x3 = 48KB -> 3 blocks/CU.
// B store: LDS[k][unit u] = W[k][n0+4*(u^(((k>>3)&1)<<2))]; read compensates
// with bc ^= ((lg&1)<<4) (both-sides, rule #21; 2-way banks = free).

#define DN_ISSUE(T, AS, BS) {                                               \
    GLL(pa0 + ((T) << 5), &AS[w << 5][0]);                                  \
    GLL(pa1 + ((T) << 5), &AS[(w << 5) + 16][0]);                           \
    GLL(pb0 + (size_t)((T) << 5) * HH, &BS[w << 3][0]);                     \
    GLL(pb1 + (size_t)((T) << 5) * HH, &BS[(w << 3) + 4][0]); }

#define DN_COMP(AS, BS) {                                                   \
    f16x8 af[2];                                                            \
    _Pragma("unroll") for (int f = 0; f < 2; ++f) {                         \
        const int m = (w << 5) + (f << 4) + lm;                             \
        af[f] = *(const f16x8*)&AS[m][(lg ^ ((m >> 1) & 3)) << 3];          \
    }                                                                       \
    _Pragma("unroll") for (int nf = 0; nf < 4; ++nf) {                      \
        const int bc = ((nf << 4) + lm) ^ ((lg & 1) << 4);                  \
        f16x8 bv;                                                           \
        _Pragma("unroll") for (int j = 0; j < 8; ++j) bv[j] = (f16)BS[(lg << 3) + j][bc]; \
        _Pragma("unroll") for (int f = 0; f < 2; ++f)                       \
            acc[f][nf] = __builtin_amdgcn_mfma_f32_16x16x32_f16(af[f], bv, acc[f][nf], 0, 0, 0); } }

#define DN_PH(T, CB, IB, VC) {                                              \
    if ((T) + 2 < 16) DN_ISSUE((T) + 2, As##IB, Bs##IB)                     \
    WAITVM(VC) BARRIER();                                                   \
    DN_COMP(As##CB, Bs##CB)                                                 \
    BARRIER(); }

__global__ __launch_bounds__(256) void down_k(
    const f16* __restrict__ rinter,
    const float* __restrict__ w_down, const float* __restrict__ ws_down,
    const int* __restrict__ counts, const int* __restrict__ offs,
    const int* __restrict__ token_list, const float* __restrict__ weight_list,
    float* __restrict__ out)
{
    const int F = blockIdx.x;
    const int Q = F & 7;
    const int J = F >> 3;                // 0..271 per XCD
    int e, n0, r0;
    if (J < 256) {                        // routed: 2 experts x 16n x 8 rowblk
        e = Q + ((J >> 7) << 3);
        const int t = J & 127;
        n0 = (t & 15) << 6;
        r0 = (t >> 4) << 7;
    } else {                              // shared: 16 tiles per XCD
        e = NE;
        const int idx = (Q << 4) + (J - 256);   // 0..127
        n0 = (idx & 15) << 6;
        r0 = (idx >> 4) << 7;
    }

    int cnt, slot0; const float* wdp;
    if (e < NE) { cnt = counts[e]; slot0 = offs[e]; wdp = w_down + (size_t)e * MM * HH; }
    else        { cnt = TT; slot0 = 2 * TT; wdp = ws_down; }
    if (r0 >= cnt) return;

    __shared__ f16  As0[128][32], As1[128][32], As2[128][32];
    __shared__ float Bs0[32][64], Bs1[32][64], Bs2[32][64];

    const int tid = threadIdx.x;
    const int w = tid >> 6, lane = tid & 63;
    const int lm = lane & 15, lg = lane >> 4;

    // A: same as gu (rows are contiguous rinter slots)
    const int swzA = ((lane & 3) ^ ((lane >> 3) & 3)) << 3;
    int ra = r0 + (w << 5) + (lane >> 2);       if (ra >= cnt) ra = cnt - 1;
    int rb = r0 + (w << 5) + 16 + (lane >> 2);  if (rb >= cnt) rb = cnt - 1;
    const f16* pa0 = rinter + (size_t)(slot0 + ra) * MM + swzA;
    const f16* pa1 = rinter + (size_t)(slot0 + rb) * MM + swzA;
    // B: GLL i covers k-rows (w<<3)+(i<<2) .. +3; lane>>4 = row-in-group,
    // lane&15 = dest 16B unit; src unit = u ^ ((w&1)<<2)
    const int sgd = 4 * ((lane & 15) ^ ((w & 1) << 2));
    const float* pb0 = wdp + (size_t)((w << 3)     + (lane >> 4)) * HH + n0 + sgd;
    const float* pb1 = wdp + (size_t)((w << 3) + 4 + (lane >> 4)) * HH + n0 + sgd;

    f32x4 acc[2][4] = {};

    DN_ISSUE(0, As0, Bs0)
    DN_ISSUE(1, As1, Bs1)

    DN_PH(0,0,2,8)  DN_PH(1,1,0,8)  DN_PH(2,2,1,8)  DN_PH(3,0,2,8)
    DN_PH(4,1,0,8)  DN_PH(5,2,1,8)  DN_PH(6,0,2,8)  DN_PH(7,1,0,8)
    DN_PH(8,2,1,8)  DN_PH(9,0,2,8)  DN_PH(10,1,0,8) DN_PH(11,2,1,8)
    DN_PH(12,0,2,8) DN_PH(13,1,0,8) DN_PH(14,2,1,4) DN_PH(15,0,0,0)

#pragma unroll
    for (int f = 0; f < 2; ++f)
#pragma unroll
        for (int rr = 0; rr < 4; ++rr) {
            const int m = (w << 5) + (f << 4) + (lg << 2) + rr;
            const int row = r0 + m;
            if (row < cnt) {
                int t; float wt;
                if (e < NE) { t = token_list[e * TT + row]; wt = weight_list[e * TT + row]; }
                else        { t = row; wt = 1.f; }
                float* orow = out + (size_t)t * HH + n0;
#pragma unroll
                for (int nf = 0; nf < 4; ++nf)
                    atomicAdd(&orow[(nf << 4) + lm], wt * acc[f][nf][rr]);
            }
        }
}

extern "C" void kernel_launch(void* const* d_in, const int* in_sizes, int n_in,
                              void* d_out, int out_size, void* d_ws, size_t ws_size,
                              hipStream_t stream)
{
    const float* x       = (const float*)d_in[0];
    const float* gate_w  = (const float*)d_in[1];
    const float* w_gate  = (const float*)d_in[2];
    const float* w_up    = (const float*)d_in[3];
    const float* w_down  = (const float*)d_in[4];
    const float* ws_gate = (const float*)d_in[5];
    const float* ws_up   = (const float*)d_in[6];
    const float* ws_down = (const float*)d_in[7];
    float* out = (float*)d_out;

    // ws (r16 layout): counts[16]|offs[17] (64 ints) | token_list 16K ints |
    // weight_list 16K floats | rinter f16 [3072][512] | xh f16 [1024][1024]
    int* counts = (int*)d_ws;
    int* offs = counts + 16;
    int* token_list = counts + 64;
    float* weight_list = (float*)(counts + 64 + NE * TT);
    f16* rinter = (f16*)(counts + 64 + 2 * NE * TT);
    f16* xh = rinter + (size_t)3072 * MM;

    hipMemsetAsync(counts, 0, 64, stream);
    hipMemsetAsync(out, 0, (size_t)TT * HH * sizeof(float), stream);
    pack_k<<<dim3(TT * HH / 1024), 256, 0, stream>>>(x, xh);
    router_k<<<dim3(TT / 4), 256, 0, stream>>>(x, gate_w, counts, token_list, weight_list);
    prefix_k<<<1, 64, 0, stream>>>(counts, offs);
    gu_k<<<dim3(8 * 272), 256, 0, stream>>>(
        xh, w_gate, w_up, ws_gate, ws_up, counts, offs, token_list, rinter);
    down_k<<<dim3(8 * 272), 256, 0, stream>>>(
        rinter, w_down, ws_down, counts, offs, token_list, weight_list, out);
}